// Round 14
// baseline (136.344 us; speedup 1.0000x reference)
//
#include <hip/hip_runtime.h>
#include <hip/hip_fp16.h>

#define SQRT3 1.7320508075688772f
#define INV_SQRT3 0.5773502691896258f
#define CAP 64

#define WAVE_SYNC() do { asm volatile("s_waitcnt lgkmcnt(0)" ::: "memory"); \
                         __builtin_amdgcn_wave_barrier(); } while (0)

// ---------------- fused prep: featH(f16) + zero block + pos4 + folded W + cnt=0 ----
// featH[node*32+cl] = half4{s_cl, v_cl0, v_cl1, v_cl2}  (256 B per node, contiguous)
// featH[N*32 ..) = zeros (padding target for the fallback path)
// WS[u*32+j], WV[u*32+o]: folded weights, row-major -> epilogue reads lane-coalesced.
__global__ void prep_kernel(const float* __restrict__ feat, const float* __restrict__ pos,
                            const float* __restrict__ Ws, const float* __restrict__ Wv,
                            const float* __restrict__ tpw,
                            uint2* __restrict__ featH, float4* __restrict__ pos4,
                            int* __restrict__ cnt,
                            float* __restrict__ WS, float* __restrict__ WV, int N) {
    int i = blockIdx.x * blockDim.x + threadIdx.x;
    int totalF = N * 32;
    if (i < totalF) {
        int node = i >> 5, cl = i & 31;
        const float* fb = feat + (size_t)node * 128;
        float s  = fb[cl];
        float v0 = fb[32 + 3 * cl], v1 = fb[33 + 3 * cl], v2 = fb[34 + 3 * cl];
        __half2 h0 = __floats2half2_rn(s, v0);
        __half2 h1 = __floats2half2_rn(v1, v2);
        uint2 r;
        r.x = *(const unsigned int*)&h0;
        r.y = *(const unsigned int*)&h1;
        featH[i] = r;
        return;
    }
    int j = i - totalF;
    if (j < 32) { featH[totalF + j] = make_uint2(0u, 0u); return; }
    j -= 32;
    if (j < N) {
        pos4[j] = make_float4(pos[3 * j], pos[3 * j + 1], pos[3 * j + 2], 0.f);
        cnt[j] = 0;
        return;
    }
    int k = j - N;
    if (k < 2048) {
        int u = k >> 5;
        float ws = Ws[k], wv = Wv[k];
        if (u < 32) {
            WS[k] = 0.125f * tpw[u] * ws;
            WV[k] = 0.125f * tpw[32 + u] * wv;
        } else {
            int uu = u - 32;
            WS[k] = 0.125f * tpw[96 + uu] * INV_SQRT3 * ws;
            WV[k] = 0.125f * tpw[64 + uu] * wv;
        }
    }
}

// ---------------- scatter with fused geometry (GG) ----------------
// slot record: uint2{ h2(gx,gy), h(gz) | src<<16 }  (8 B).  cnt[d] ends as degree.
__global__ void scatter_gg_kernel(const int* __restrict__ esrc, const int* __restrict__ edst,
                                  const float4* __restrict__ pos4,
                                  int* __restrict__ cnt, uint2* __restrict__ geomH, int E) {
    int t = blockIdx.x * blockDim.x + threadIdx.x;
    int e0 = t * 4;
    auto doEdge = [&](int s, int d) {
        int p = atomicAdd(&cnt[d], 1);
        if (p < CAP) {
            float4 pd = pos4[d], ps = pos4[s];
            float ex = pd.x - ps.x, ey = pd.y - ps.y, ez = pd.z - ps.z;
            float rr = SQRT3 * rsqrtf(ex * ex + ey * ey + ez * ez + 1e-12f);
            __half2 hxy = __floats2half2_rn(rr * ex, rr * ey);
            __half  hz  = __float2half_rn(rr * ez);
            uint2 g;
            g.x = *(const unsigned int*)&hxy;
            g.y = (unsigned)(*(const unsigned short*)&hz) | ((unsigned)s << 16);
            geomH[(size_t)d * CAP + p] = g;
        }
    };
    if (e0 + 4 <= E) {
        int4 s4 = *(const int4*)(esrc + e0);
        int4 d4 = *(const int4*)(edst + e0);
        doEdge(s4.x, d4.x); doEdge(s4.y, d4.y); doEdge(s4.z, d4.z); doEdge(s4.w, d4.w);
    } else {
        for (int e = e0; e < E; ++e) doEdge(esrc[e], edst[e]);
    }
}

// ---------------- plain scatter (fallback, proven R7/R13) ----------------
__global__ void scatter_kernel(const int* __restrict__ esrc, const int* __restrict__ edst,
                               int* __restrict__ cnt, int* __restrict__ csrP, int E) {
    int t = blockIdx.x * blockDim.x + threadIdx.x;
    int e0 = t * 4;
    if (e0 + 4 <= E) {
        int4 s4 = *(const int4*)(esrc + e0);
        int4 d4 = *(const int4*)(edst + e0);
        int p;
        p = atomicAdd(&cnt[d4.x], 1); if (p < CAP) csrP[(size_t)d4.x * CAP + p] = s4.x;
        p = atomicAdd(&cnt[d4.y], 1); if (p < CAP) csrP[(size_t)d4.y * CAP + p] = s4.y;
        p = atomicAdd(&cnt[d4.z], 1); if (p < CAP) csrP[(size_t)d4.z * CAP + p] = s4.z;
        p = atomicAdd(&cnt[d4.w], 1); if (p < CAP) csrP[(size_t)d4.w * CAP + p] = s4.w;
    } else {
        for (int e = e0; e < E; ++e) {
            int d = edst[e];
            int p = atomicAdd(&cnt[d], 1);
            if (p < CAP) csrP[(size_t)d * CAP + p] = esrc[e];
        }
    }
}

// ---------------- per-node gather + TP + linear ----------------
// GG=1: NO geometry phase, NO in-loop LDS/sync. Per body: 8B geom record
// (row-sequential, broadcast) + 8B featH gather + ~17 VALU. Padded slots masked.
// GG=0: proven R13 structure (LDS geometry phase + zero-block padding).

template<bool GG>
__global__ __launch_bounds__(256) void node_kernel(
    const uint2* __restrict__ featH, const float4* __restrict__ pos4,
    const int* __restrict__ csrP, const uint2* __restrict__ geomH,
    const int* __restrict__ cnt,
    const float* __restrict__ WS, const float* __restrict__ WV,
    float* __restrict__ out, int N)
{
    __shared__ float4 geom[4][GG ? 1 : 64];
    __shared__ float  sS[4][68], sX[4][68], sY[4][68], sZ[4][68];
    int lane = threadIdx.x & 63;
    int w    = threadIdx.x >> 6;
    int node = blockIdx.x * 4 + w;
    if (node >= N) return;                 // whole-wave exit; no block barriers used

    int deg = cnt[node];                   // cursor after scatter == degree
    int len = deg < CAP ? deg : CAP;
    int lenP = (len + 7) & ~7;             // padded length (multiple of 8, <= 64)
    int half = lane >> 5;
    int cl   = lane & 31;

    float A0 = 0.f, A1x = 0.f, A1y = 0.f, A1z = 0.f;   // s-channel cl: a0, a1
    float V0 = 0.f, V1 = 0.f, V2 = 0.f, T3 = 0.f;      // v-channel cl: a2, a3(raw)

    if constexpr (GG) {
        const uint2* grow = geomH + (size_t)node * CAP;
        #pragma unroll 4
        for (int m = 0; m + 2 <= lenP; m += 2) {
            int e = m + half;
            uint2 ge = grow[e];
            bool ok = e < len;
            float2 gxy = __half22float2(*(const __half2*)&ge.x);
            unsigned short uz = (unsigned short)(ge.y & 0xFFFFu);
            float gz = __half2float(*(const __half*)&uz);
            int si = ok ? (int)(ge.y >> 16) : 0;
            unsigned msk = ok ? 0xFFFFFFFFu : 0u;
            uint2 fr = featH[(size_t)si * 32 + cl];
            fr.x &= msk; fr.y &= msk;
            float2 lo = __half22float2(*(const __half2*)&fr.x);   // {s, v0}
            float2 hi = __half22float2(*(const __half2*)&fr.y);   // {v1, v2}
            A0 += lo.x;
            A1x = fmaf(lo.x, gxy.x, A1x); A1y = fmaf(lo.x, gxy.y, A1y); A1z = fmaf(lo.x, gz, A1z);
            V0 += lo.y; V1 += hi.x; V2 += hi.y;
            T3 = fmaf(lo.y, gxy.x, fmaf(hi.x, gxy.y, fmaf(hi.y, gz, T3)));
        }
    } else {
        float4 pd = pos4[node];            // wave-uniform
        if (lane < len) {
            int s = csrP[(size_t)node * CAP + lane];
            float4 ps = pos4[s];
            float ex = pd.x - ps.x, ey = pd.y - ps.y, ez = pd.z - ps.z;
            float rr = SQRT3 * rsqrtf(ex * ex + ey * ey + ez * ez + 1e-12f);
            geom[w][lane] = make_float4(rr * ex, rr * ey, rr * ez, __int_as_float(s));
        } else {
            geom[w][lane] = make_float4(0.f, 0.f, 0.f, __int_as_float(N));
        }
        WAVE_SYNC();
        #pragma unroll 4
        for (int m = 0; m + 2 <= lenP; m += 2) {
            float4 g = geom[w][m + half];
            int si = __float_as_int(g.w);
            uint2 fr = featH[(size_t)si * 32 + cl];
            float2 lo = __half22float2(*(const __half2*)&fr.x);
            float2 hi = __half22float2(*(const __half2*)&fr.y);
            A0 += lo.x;
            A1x = fmaf(lo.x, g.x, A1x); A1y = fmaf(lo.x, g.y, A1y); A1z = fmaf(lo.x, g.z, A1z);
            V0 += lo.y; V1 += hi.x; V2 += hi.y;
            T3 = fmaf(lo.y, g.x, fmaf(hi.x, g.y, fmaf(hi.y, g.z, T3)));
        }
    }

    // cross-half reduce (lanes L, L+32 hold same channel over disjoint edges)
    A0 += __shfl_xor(A0, 32);  A1x += __shfl_xor(A1x, 32);
    A1y += __shfl_xor(A1y, 32); A1z += __shfl_xor(A1z, 32);
    V0 += __shfl_xor(V0, 32);  V1 += __shfl_xor(V1, 32);
    V2 += __shfl_xor(V2, 32);  T3 += __shfl_xor(T3, 32);

    // SoA aggregate: [0,32)=s-path raw {A0 | A1x/y/z}, [32,64)=v-path raw {T3 | V0/1/2}
    int k = half ? (32 + cl) : cl;
    sS[w][k] = half ? T3 : A0;
    sX[w][k] = half ? V0 : A1x;
    sY[w][k] = half ? V1 : A1y;
    sZ[w][k] = half ? V2 : A1z;
    WAVE_SYNC();

    // epilogue: outputs j = lane, lane+64; weight reads lane-coalesced (proven R7)
    size_t ob = (size_t)node * 128;
    #pragma unroll
    for (int t = 0; t < 2; ++t) {
        int j = lane + 64 * t;
        const float *ap, *wp;
        if (j < 32) {
            ap = sS[w]; wp = WS + j;
        } else {
            int v = j - 32;
            int o = v / 3, mm = v - 3 * o;
            ap = (mm == 0) ? sX[w] : (mm == 1) ? sY[w] : sZ[w];
            wp = WV + o;
        }
        float r = 0.f;
        #pragma unroll
        for (int q = 0; q < 16; ++q) {
            float4 a = *(const float4*)(ap + 4 * q);
            r = fmaf(a.x, wp[(4 * q + 0) * 32], r);
            r = fmaf(a.y, wp[(4 * q + 1) * 32], r);
            r = fmaf(a.z, wp[(4 * q + 2) * 32], r);
            r = fmaf(a.w, wp[(4 * q + 3) * 32], r);
        }
        out[ob + j] = r;                   // all scales folded into WS/WV
    }
}

extern "C" void kernel_launch(void* const* d_in, const int* in_sizes, int n_in,
                              void* d_out, int out_size, void* d_ws, size_t ws_size,
                              hipStream_t stream) {
    const float* feat = (const float*)d_in[0];
    const float* pos  = (const float*)d_in[1];
    const int*   esrc = (const int*)d_in[2];
    const int*   edst = (const int*)d_in[3];
    const float* tpw  = (const float*)d_in[4];
    const float* Ws   = (const float*)d_in[5];
    const float* Wv   = (const float*)d_in[6];
    float* out = (float*)d_out;

    int N = in_sizes[0] / 128;
    int E = in_sizes[2];

    // common prefix
    uint2*  featH = (uint2*)d_ws;                            // (N+1)*32 uint2
    float4* pos4  = (float4*)(featH + (size_t)(N + 1) * 32); // N
    char*   rest  = (char*)(pos4 + N);

    size_t slotsGG = (size_t)N * CAP * 8;    // geomH  (8 B/slot)
    size_t slotsPL = (size_t)N * CAP * 4;    // csrP   (4 B/slot)
    size_t fixed   = (size_t)(N + 1) * 256 + (size_t)N * 16 + (size_t)N * 4 + 16384 + 256;
    bool gg = (N <= 65535) && (ws_size >= fixed + slotsGG);

    uint2* geomH = nullptr; int* csrP = nullptr; int* cnt; float* WS; float* WV;
    if (gg) {
        geomH = (uint2*)rest;
        cnt   = (int*)(geomH + (size_t)N * CAP);
    } else {
        csrP  = (int*)rest;
        cnt   = csrP + (size_t)N * CAP;
    }
    WS = (float*)(cnt + N);
    WV = WS + 2048;

    const int tb = 256;
    int prepTot = N * 32 + 32 + N + 2048;
    int ebk = (E / 4 + tb) / tb;
    int nblocks = (N + 3) / 4;

    prep_kernel<<<(prepTot + tb - 1) / tb, tb, 0, stream>>>(feat, pos, Ws, Wv, tpw,
                                                            featH, pos4, cnt, WS, WV, N);
    if (gg) {
        scatter_gg_kernel<<<ebk, tb, 0, stream>>>(esrc, edst, pos4, cnt, geomH, E);
        node_kernel<true><<<nblocks, 256, 0, stream>>>(featH, pos4, csrP, geomH, cnt,
                                                       WS, WV, out, N);
    } else {
        scatter_kernel<<<ebk, tb, 0, stream>>>(esrc, edst, cnt, csrP, E);
        node_kernel<false><<<nblocks, 256, 0, stream>>>(featH, pos4, csrP, geomH, cnt,
                                                        WS, WV, out, N);
    }
}

// Round 15
// 107.535 us; speedup vs baseline: 1.2679x; 1.2679x over previous
//
#include <hip/hip_runtime.h>
#include <hip/hip_fp16.h>

#define SQRT3 1.7320508075688772f
#define INV_SQRT3 0.5773502691896258f
#define CAP 64

#define WAVE_SYNC() do { asm volatile("s_waitcnt lgkmcnt(0)" ::: "memory"); \
                         __builtin_amdgcn_wave_barrier(); } while (0)

// ---------------- fused prep: featH(f16) + pos4 + folded h2-packed weights + cnt=0 ----
// featH[node*32+cl] = half4{s_cl, v_cl0, v_cl1, v_cl2}  (256 B per node, contiguous)
// WS2[u2*32+j] = h2{ fs(2u2,j), fs(2u2+1,j) },  fs(u,j) = 0.125*w0[u]*Ws[u][j]      (u<32)
//                                               fs(u,j) = 0.125*w3[u-32]/sqrt3*Ws[u][j]
// WV2[u2*32+o] = h2{ fv(2u2,o), fv(2u2+1,o) },  fv(u,o) = 0.125*w1[u]*Wv[u][o]      (u<32)
//                                               fv(u,o) = 0.125*w2[u-32]*Wv[u][o]
__global__ void prep_kernel(const float* __restrict__ feat, const float* __restrict__ pos,
                            const float* __restrict__ Ws, const float* __restrict__ Wv,
                            const float* __restrict__ tpw,
                            uint2* __restrict__ featH, float4* __restrict__ pos4,
                            int* __restrict__ cnt,
                            __half2* __restrict__ WS2, __half2* __restrict__ WV2, int N) {
    int i = blockIdx.x * blockDim.x + threadIdx.x;
    int totalF = N * 32;
    if (i < totalF) {
        int node = i >> 5, cl = i & 31;
        const float* fb = feat + (size_t)node * 128;
        float s  = fb[cl];
        float v0 = fb[32 + 3 * cl], v1 = fb[33 + 3 * cl], v2 = fb[34 + 3 * cl];
        __half2 h0 = __floats2half2_rn(s, v0);
        __half2 h1 = __floats2half2_rn(v1, v2);
        uint2 r;
        r.x = *(const unsigned int*)&h0;
        r.y = *(const unsigned int*)&h1;
        featH[i] = r;
        return;
    }
    int j = i - totalF;
    if (j < N) {
        pos4[j] = make_float4(pos[3 * j], pos[3 * j + 1], pos[3 * j + 2], 0.f);
        cnt[j] = 0;                        // zero scatter cursors (no memset pass)
        return;
    }
    int k = j - N;
    if (k < 1024) {                        // u2 = k>>5 in [0,32), col = k&31
        int u2 = k >> 5, c = k & 31;
        int ua = 2 * u2, ub = 2 * u2 + 1;
        auto fs = [&](int u) {
            float w = Ws[u * 32 + c];
            return (u < 32) ? 0.125f * tpw[u] * w
                            : 0.125f * tpw[96 + (u - 32)] * INV_SQRT3 * w;
        };
        auto fv = [&](int u) {
            float w = Wv[u * 32 + c];
            return (u < 32) ? 0.125f * tpw[32 + u] * w
                            : 0.125f * tpw[64 + (u - 32)] * w;
        };
        WS2[k] = __floats2half2_rn(fs(ua), fs(ub));
        WV2[k] = __floats2half2_rn(fv(ua), fv(ub));
    }
}

// ---------------- single-pass padded-CSR scatter (proven R7, byte-identical) --------
__global__ void scatter_kernel(const int* __restrict__ esrc, const int* __restrict__ edst,
                               int* __restrict__ cnt, int* __restrict__ csrP, int E) {
    int t = blockIdx.x * blockDim.x + threadIdx.x;
    int e0 = t * 4;
    if (e0 + 4 <= E) {
        int4 s4 = *(const int4*)(esrc + e0);
        int4 d4 = *(const int4*)(edst + e0);
        int p;
        p = atomicAdd(&cnt[d4.x], 1); if (p < CAP) csrP[(size_t)d4.x * CAP + p] = s4.x;
        p = atomicAdd(&cnt[d4.y], 1); if (p < CAP) csrP[(size_t)d4.y * CAP + p] = s4.y;
        p = atomicAdd(&cnt[d4.z], 1); if (p < CAP) csrP[(size_t)d4.z * CAP + p] = s4.z;
        p = atomicAdd(&cnt[d4.w], 1); if (p < CAP) csrP[(size_t)d4.w * CAP + p] = s4.w;
    } else {
        for (int e = e0; e < E; ++e) {
            int d = edst[e];
            int p = atomicAdd(&cnt[d], 1);
            if (p < CAP) csrP[(size_t)d * CAP + p] = esrc[e];
        }
    }
}

// ---------------- per-node gather + TP + linear (EXACT R7 structure) ----------------
// 1 wave/node, HALF-wave per edge, lane owns channel cl = {s,v0,v1,v2} (f16x4, 8B).
// Geometry phase in LDS (si packed in geom.w); unroll-4 runtime loop + odd tail;
// epilogue lane-coalesced with h2-packed weights (64 VMEM instead of 128).

__global__ __launch_bounds__(256) void node_kernel(
    const uint2* __restrict__ featH, const float4* __restrict__ pos4,
    const int* __restrict__ csrP, const int* __restrict__ cnt,
    const __half2* __restrict__ WS2, const __half2* __restrict__ WV2,
    float* __restrict__ out, int N)
{
    __shared__ float4 geom[4][64];
    __shared__ float  sS[4][68], sX[4][68], sY[4][68], sZ[4][68];
    int lane = threadIdx.x & 63;
    int w    = threadIdx.x >> 6;
    int node = blockIdx.x * 4 + w;
    if (node >= N) return;                 // whole-wave exit; no block barriers used

    int deg = cnt[node];                   // cursor after scatter == degree
    int len = deg < CAP ? deg : CAP;
    int half = lane >> 5;
    int cl   = lane & 31;

    float4 pd = pos4[node];                // wave-uniform

    if (lane < len) {
        int s = csrP[(size_t)node * CAP + lane];
        float4 ps = pos4[s];
        float ex = pd.x - ps.x, ey = pd.y - ps.y, ez = pd.z - ps.z;
        float rr = SQRT3 * rsqrtf(ex * ex + ey * ey + ez * ez + 1e-12f);
        geom[w][lane] = make_float4(rr * ex, rr * ey, rr * ez, __int_as_float(s));
    }
    WAVE_SYNC();

    float A0 = 0.f, A1x = 0.f, A1y = 0.f, A1z = 0.f;   // s-channel cl: a0, a1
    float V0 = 0.f, V1 = 0.f, V2 = 0.f, T3 = 0.f;      // v-channel cl: a2, a3(raw)

    int even = len & ~1;
    #pragma unroll 4
    for (int m = 0; m < even; m += 2) {
        float4 g = geom[w][m + half];
        int si = __float_as_int(g.w);
        uint2 fr = featH[(size_t)si * 32 + cl];
        float2 lo = __half22float2(*(const __half2*)&fr.x);   // {s, v0}
        float2 hi = __half22float2(*(const __half2*)&fr.y);   // {v1, v2}
        A0 += lo.x;
        A1x = fmaf(lo.x, g.x, A1x); A1y = fmaf(lo.x, g.y, A1y); A1z = fmaf(lo.x, g.z, A1z);
        V0 += lo.y; V1 += hi.x; V2 += hi.y;
        T3 = fmaf(lo.y, g.x, fmaf(hi.x, g.y, fmaf(hi.y, g.z, T3)));
    }
    if (len & 1) {                         // odd tail: half 0 only
        if (half == 0) {
            float4 g = geom[w][len - 1];
            int si = __float_as_int(g.w);
            uint2 fr = featH[(size_t)si * 32 + cl];
            float2 lo = __half22float2(*(const __half2*)&fr.x);
            float2 hi = __half22float2(*(const __half2*)&fr.y);
            A0 += lo.x;
            A1x = fmaf(lo.x, g.x, A1x); A1y = fmaf(lo.x, g.y, A1y); A1z = fmaf(lo.x, g.z, A1z);
            V0 += lo.y; V1 += hi.x; V2 += hi.y;
            T3 = fmaf(lo.y, g.x, fmaf(hi.x, g.y, fmaf(hi.y, g.z, T3)));
        }
    }

    // cross-half reduce (lanes L, L+32 hold same channel over disjoint edges)
    A0 += __shfl_xor(A0, 32);  A1x += __shfl_xor(A1x, 32);
    A1y += __shfl_xor(A1y, 32); A1z += __shfl_xor(A1z, 32);
    V0 += __shfl_xor(V0, 32);  V1 += __shfl_xor(V1, 32);
    V2 += __shfl_xor(V2, 32);  T3 += __shfl_xor(T3, 32);

    // SoA aggregate: [0,32)=s-path raw {A0 | A1x/y/z}, [32,64)=v-path raw {T3 | V0/1/2}
    int k = half ? (32 + cl) : cl;
    sS[w][k] = half ? T3 : A0;
    sX[w][k] = half ? V0 : A1x;
    sY[w][k] = half ? V1 : A1y;
    sZ[w][k] = half ? V2 : A1z;
    WAVE_SYNC();

    // epilogue: outputs j = lane, lane+64; h2-packed weights, lane-coalesced loads
    size_t ob = (size_t)node * 128;
    #pragma unroll
    for (int t = 0; t < 2; ++t) {
        int j = lane + 64 * t;
        const float *ap;
        const __half2 *wp2;
        if (j < 32) {
            ap = sS[w]; wp2 = WS2 + j;
        } else {
            int v = j - 32;
            int o = v / 3, mm = v - 3 * o;
            ap = (mm == 0) ? sX[w] : (mm == 1) ? sY[w] : sZ[w];
            wp2 = WV2 + o;
        }
        float r = 0.f;
        #pragma unroll
        for (int q = 0; q < 16; ++q) {
            float4 a = *(const float4*)(ap + 4 * q);
            float2 w0 = __half22float2(wp2[(2 * q)     * 32]);
            float2 w1 = __half22float2(wp2[(2 * q + 1) * 32]);
            r = fmaf(a.x, w0.x, r); r = fmaf(a.y, w0.y, r);
            r = fmaf(a.z, w1.x, r); r = fmaf(a.w, w1.y, r);
        }
        out[ob + j] = r;                   // all scales folded into WS2/WV2
    }
}

extern "C" void kernel_launch(void* const* d_in, const int* in_sizes, int n_in,
                              void* d_out, int out_size, void* d_ws, size_t ws_size,
                              hipStream_t stream) {
    const float* feat = (const float*)d_in[0];
    const float* pos  = (const float*)d_in[1];
    const int*   esrc = (const int*)d_in[2];
    const int*   edst = (const int*)d_in[3];
    const float* tpw  = (const float*)d_in[4];
    const float* Ws   = (const float*)d_in[5];
    const float* Wv   = (const float*)d_in[6];
    float* out = (float*)d_out;

    int N = in_sizes[0] / 128;
    int E = in_sizes[2];

    uint2*   featH = (uint2*)d_ws;                      // N*32   (12.8 MB, 256 B/node)
    float4*  pos4  = (float4*)(featH + (size_t)N * 32); // N      (0.8 MB)
    int*     csrP  = (int*)(pos4 + N);                  // N*CAP  (12.8 MB)
    int*     cnt   = csrP + (size_t)N * CAP;            // N      (0.2 MB)
    __half2* WS2   = (__half2*)(cnt + N);               // 1024   (4 KB)
    __half2* WV2   = WS2 + 1024;                        // 1024   (4 KB)

    const int tb = 256;
    int prepTot = N * 32 + N + 1024;
    int ebk = (E / 4 + tb) / tb;
    prep_kernel<<<(prepTot + tb - 1) / tb, tb, 0, stream>>>(feat, pos, Ws, Wv, tpw,
                                                            featH, pos4, cnt, WS2, WV2, N);
    scatter_kernel<<<ebk, tb, 0, stream>>>(esrc, edst, cnt, csrP, E);
    node_kernel<<<(N + 3) / 4, 256, 0, stream>>>(featH, pos4, csrP, cnt, WS2, WV2, out, N);
}